// Round 8
// baseline (45.036 us; speedup 1.0000x reference)
//
#include <hip/hip_runtime.h>
#include <math.h>

// BalNoisedTopK: loss = mean_i relu(1 + mean_j kth_max(s_i + Z_ij, excl y_i) - s_{i,y_i})
// s: (n, d) f32, y: (n,) i32, Z: (n, d, m) f32 (m innermost), out: scalar f32.
// K=5, m=8, eps=1.0 compile-time constants per the reference.
//
// R7 base + single change: Z is loaded as float4 (16B/lane, wave reads 1KB
// contiguous = 4x fewer VMEM requests) and transposed through a 1KB per-wave
// LDS tile back to the R4 per-lane ownership (sample t&7, distinct elements).
// ds_write_b128 at dword 4*lane; ds_read_b32 at dword lane+64k (linear,
// conflict-free). All downstream merge/tail logic identical to R4/R7.

#define KTOP 5
#define MSAMP 8
#define TPB 256
#define NCHUNKS 32
#define SLDS 3200   // max staged chunk elements (nchunks=32 -> chunk=3200)
#define EPW 32      // elements per wave-tile (32 elems x 8 samples = 1KB)

// v sorted ascending; v[0] = current 5th-largest. Branchless insert:
// new v[q] = median(x, v[q], v[q+1]) == clamp(x, v[q], v[q+1]) since v sorted.
__device__ __forceinline__ void topk_insert_bl(float (&v)[KTOP], float x) {
    float n0 = __builtin_amdgcn_fmed3f(x, v[0], v[1]);
    float n1 = __builtin_amdgcn_fmed3f(x, v[1], v[2]);
    float n2 = __builtin_amdgcn_fmed3f(x, v[2], v[3]);
    float n3 = __builtin_amdgcn_fmed3f(x, v[3], v[4]);
    float n4 = fmaxf(v[4], x);
    v[0] = n0; v[1] = n1; v[2] = n2; v[3] = n3; v[4] = n4;
}

__global__ __launch_bounds__(TPB) void topk_partial(
    const float* __restrict__ s, const int* __restrict__ y,
    const float* __restrict__ Z, float* __restrict__ cand,
    int d, int nchunks, int chunk)
{
    const int i = blockIdx.x / nchunks;
    const int c = blockIdx.x % nchunks;
    const int e0 = c * chunk;                 // chunk is 128-aligned
    const int e1 = min(e0 + chunk, d);
    const int yi = y[i];

    const int t = threadIdx.x;
    const int wave = t >> 6;
    const int lane = t & 63;

    const float* __restrict__ srow = s + (size_t)i * d;
    const float* __restrict__ zrow = Z + (size_t)i * d * MSAMP;

    // ---- stage s-chunk into LDS (coalesced float4), as R7 ----
    __shared__ __align__(16) float s_lds[SLDS];
    const int clen = e1 - e0;
    {
        const int nv4 = clen > 0 ? (clen >> 2) : 0;
        for (int w = t; w < nv4; w += TPB) {
            float4 vv = *(const float4*)(srow + e0 + (size_t)w * 4);
            *(float4*)(s_lds + w * 4) = vv;
        }
        for (int w = (nv4 << 2) + t; w < clen; w += TPB)
            s_lds[w] = srow[e0 + w];
        __syncthreads();
    }

    // ---- main loop: float4 Z loads, per-wave LDS transpose tile ----
    __shared__ __align__(16) float zbuf[TPB / 64][EPW * MSAMP];  // 1KB/wave
    float* __restrict__ zb = zbuf[wave];

    const int E  = lane >> 1;        // owned element within tile (0..31)
    const int h4 = (lane & 1) * 4;   // owned sample quad (0 or 4)

    float v[KTOP];
    #pragma unroll
    for (int q = 0; q < KTOP; ++q) v[q] = -INFINITY;

    int eb = e0 + wave * EPW;        // this wave's tile base; stride 128
    float4 z4 = make_float4(0.f, 0.f, 0.f, 0.f);
    if (eb < e1) {
        int ea = min(eb + E, e1 - 1);
        z4 = *(const float4*)(zrow + (size_t)ea * MSAMP + h4);
    }
    for (; eb < e1; eb += 4 * EPW) {
        float4 cur = z4;
        int ebn = eb + 4 * EPW;
        if (ebn < e1) {              // prefetch next tile (wave-uniform branch)
            int ea = min(ebn + E, e1 - 1);
            z4 = *(const float4*)(zrow + (size_t)ea * MSAMP + h4);
        }
        *(float4*)(zb + 4 * lane) = cur;   // transpose tile into LDS
        #pragma unroll
        for (int k = 0; k < 4; ++k) {
            const int er = eb + (lane >> 3) + 8 * k;   // element id
            float sv = s_lds[er - e0];                 // 8-lane broadcast
            float z  = zb[lane + 64 * k];              // linear, conflict-free
            float x  = (er < e1 && er != yi) ? (sv + z) : -INFINITY;
            topk_insert_bl(v, x);
        }
    }

    // Butterfly merge across the 8 lanes sharing sample j = lane&7 (xor
    // 8/16/32 preserves lane&7). Afterwards lane holds wave's per-sample top5.
    #pragma unroll
    for (int off = 8; off <= 32; off <<= 1) {
        float o[KTOP];
        #pragma unroll
        for (int q = 0; q < KTOP; ++q) o[q] = __shfl_xor(v[q], off, 64);
        #pragma unroll
        for (int q = 0; q < KTOP; ++q) topk_insert_bl(v, o[q]);
    }

    __shared__ float lds[TPB / 64][MSAMP][KTOP];
    if (lane < MSAMP) {
        #pragma unroll
        for (int q = 0; q < KTOP; ++q) lds[wave][lane][q] = v[q];
    }
    __syncthreads();

    if (t < MSAMP) {
        float f[KTOP];
        #pragma unroll
        for (int q = 0; q < KTOP; ++q) f[q] = lds[0][t][q];
        #pragma unroll
        for (int w = 1; w < TPB / 64; ++w)
            #pragma unroll
            for (int q = 0; q < KTOP; ++q) topk_insert_bl(f, lds[w][t][q]);
        float* out = cand + (((size_t)i * nchunks + c) * MSAMP + t) * KTOP;
        #pragma unroll
        for (int q = 0; q < KTOP; ++q) out[q] = f[q];
    }
}

// One block per row i; 256 threads: thread t -> chunk c = t>>3, sample j = t&7.
// Merges chunk candidates (butterfly over c within wave, LDS across waves),
// averages kth over samples, writes the row hinge loss.
__global__ __launch_bounds__(TPB) void row_loss(
    const float* __restrict__ s, const int* __restrict__ y,
    const float* __restrict__ cand, float* __restrict__ rloss,
    int d, int nchunks)
{
    const int i = blockIdx.x;
    const int t = threadIdx.x;
    const int j = t & 7;
    const int wave = t >> 6;
    const int lane = t & 63;

    float v[KTOP];
    #pragma unroll
    for (int q = 0; q < KTOP; ++q) v[q] = -INFINITY;

    for (int c = t >> 3; c < nchunks; c += TPB / MSAMP) {
        const float* p = cand + (((size_t)i * nchunks + c) * MSAMP + j) * KTOP;
        #pragma unroll
        for (int q = 0; q < KTOP; ++q) topk_insert_bl(v, p[q]);
    }

    // Merge across the 8 chunk-slots sharing sample j inside this wave.
    #pragma unroll
    for (int off = 8; off <= 32; off <<= 1) {
        float o[KTOP];
        #pragma unroll
        for (int q = 0; q < KTOP; ++q) o[q] = __shfl_xor(v[q], off, 64);
        #pragma unroll
        for (int q = 0; q < KTOP; ++q) topk_insert_bl(v, o[q]);
    }

    __shared__ float lds[TPB / 64][MSAMP][KTOP];
    __shared__ float kth_j[MSAMP];
    if (lane < MSAMP) {
        #pragma unroll
        for (int q = 0; q < KTOP; ++q) lds[wave][lane][q] = v[q];
    }
    __syncthreads();

    if (t < MSAMP) {
        float f[KTOP];
        #pragma unroll
        for (int q = 0; q < KTOP; ++q) f[q] = lds[0][t][q];
        #pragma unroll
        for (int w = 1; w < TPB / 64; ++w)
            #pragma unroll
            for (int q = 0; q < KTOP; ++q) topk_insert_bl(f, lds[w][t][q]);
        kth_j[t] = f[0];                 // exact 5th-largest for (i, j=t)
    }
    __syncthreads();

    if (t == 0) {
        float sum = 0.0f;
        #pragma unroll
        for (int jj = 0; jj < MSAMP; ++jj) sum += kth_j[jj];
        float kth_smooth = sum * (1.0f / (float)MSAMP);
        float sy = s[(size_t)i * d + y[i]];
        rloss[i] = fmaxf(1.0f + kth_smooth - sy, 0.0f);
    }
}

__global__ __launch_bounds__(64) void mean_loss(
    const float* __restrict__ rloss, float* __restrict__ out, int n)
{
    const int t = threadIdx.x;
    float x = (t < n) ? rloss[t] : 0.0f;
    #pragma unroll
    for (int off = 32; off >= 1; off >>= 1) x += __shfl_xor(x, off, 64);
    if (t == 0) out[0] = x / (float)n;
}

extern "C" void kernel_launch(void* const* d_in, const int* in_sizes, int n_in,
                              void* d_out, int out_size, void* d_ws, size_t ws_size,
                              hipStream_t stream) {
    const float* s = (const float*)d_in[0];
    const int*   y = (const int*)d_in[1];
    const float* Z = (const float*)d_in[2];
    float* out = (float*)d_out;

    const int n = in_sizes[1];
    const int d = in_sizes[0] / n;

    int nchunks = NCHUNKS;
    while (nchunks > 1 &&
           (size_t)n * nchunks * MSAMP * KTOP * sizeof(float) + n * sizeof(float)
               > ws_size) {
        nchunks >>= 1;
    }
    int chunk = (d + nchunks - 1) / nchunks;
    chunk = (chunk + 127) & ~127;         // 128-aligned (4 wave-tiles of 32)
    float* cand  = (float*)d_ws;
    float* rloss = cand + (size_t)n * nchunks * MSAMP * KTOP;

    hipLaunchKernelGGL(topk_partial, dim3(n * nchunks), dim3(TPB), 0, stream,
                       s, y, Z, cand, d, nchunks, chunk);
    hipLaunchKernelGGL(row_loss, dim3(n), dim3(TPB), 0, stream,
                       s, y, cand, rloss, d, nchunks);
    hipLaunchKernelGGL(mean_loss, dim3(1), dim3(64), 0, stream,
                       rloss, out, n);
}